// Round 5
// baseline (361.479 us; speedup 1.0000x reference)
//
#include <hip/hip_runtime.h>
#include <cstdint>
#include <cstddef>

// ============================================================================
// CellSetAttentionNetwork: X[8,2048,512] fp32, single-head attention D=H=512.
// Pipeline: cvt(all) -> QKV gemm -> scores gemm (exp + rowsum fused) ->
//           PV gemm (1/rowsum fused) -> out gemm -> layernorm.
// R11: latency-exposure fix. R10 post-mortem: XCD swizzle worked (FETCH
// 68.7->21.7MB) yet time flat -> staging is LATENCY-bound, not BW-bound
// (m97 family delivers ~14 TB/s; we got 4.8-7.1). Occupancy pinned ~8
// waves/CU all session (2x4-wave or 1x8-wave blocks); depth-2 prefetch
// covers ~1000cy vs ~900cy miss latency - marginal. Fix both:
//  - depth-3 prefetch: 4 LDS buffers, s_waitcnt vmcnt(2*PW) mid-loop
//    (3 iter-times ~2100cy coverage), never drains to 0 mid-loop.
//  - 128x128 tiles @ 8 waves (512thr, wave-tile 64x32, PW=2): LDS = 4x16KB
//    = 64KB -> 2 blocks/CU co-resident = 16 waves/CU (2x all prior rounds).
// Flash fusion evaluated and shelved: D=H=512 makes Q/V tiles too fat
// (1 block/CU at 160KB LDS, or 2x scores recompute).
// Softmax max-free: scores stores E=exp(s*scale)+rowsum atomics; PV divides.
//
// ws layout (byte offsets):
//   [0, 64M)      S/E [8][2048][2048] bf16
//   [0, 16M)      Xb  [16384][512] bf16 (overlay: dead before S written)
//   [64M, +2M)    Wt  [2048][512] bf16 (Wq^T,Wk^T,Wv^T,Wo^T stacked)
//   [66M, +16M)   q   [16384][512] bf16; reused as ctx after scores gemm
//   [82M, +16M)   k   [16384][512] bf16
//   [98M, +16M)   vT  [8][512][2048] bf16
//   [114M, +64K)  rowsum fp32[16384]
// ============================================================================

typedef __bf16 bf16x8 __attribute__((ext_vector_type(8)));
typedef float  f32x4  __attribute__((ext_vector_type(4)));

__device__ __forceinline__ uint16_t f2bf(float f) {
  union { float f; uint32_t u; } v; v.f = f;
  uint32_t r = v.u + 0x7FFFu + ((v.u >> 16) & 1u);   // RNE
  return (uint16_t)(r >> 16);
}

__device__ __forceinline__ void gld16(const uint16_t* g, uint16_t* l) {
  // async global->LDS, 16B per lane; LDS dest = wave-uniform base + lane*16
  __builtin_amdgcn_global_load_lds(
      (__attribute__((address_space(1))) void*)(g),
      (__attribute__((address_space(3))) void*)(l), 16, 0, 0);
}

// MODE 0: QKV   (out q, k normal [M][512]; v transposed vT[b][h][t], +bias)
// MODE 1: scores (out bf16 E=exp(s*scale), rowsum atomics), batch = z
// MODE 2: ctx = (E @ vT^T)/rowsum  (out bf16 [b*2048+n][512]), batch = z
// MODE 3: out-proj (+bo +X residual, fp32 out)
// 8 waves (512 thr) in WMxWN grid (WM*WN==8), wave tile (BM/WM)x(BN/WN);
// BM,BN multiples of 128; K % 32 == 0, K/32 >= 3 (depth-3 prologue).
template <int MODE, int BM, int BN, int WM, int WN>
__global__ __launch_bounds__(512, 4) void gemm_k(
    const uint16_t* __restrict__ A, const uint16_t* __restrict__ Bt,
    void* __restrict__ OutA, uint16_t* __restrict__ OutK,
    uint16_t* __restrict__ OutVT, float* __restrict__ rsum, int K, int lda,
    int ldb, const float* __restrict__ b0, const float* __restrict__ b1,
    const float* __restrict__ b2, const float* __restrict__ Xres, float scale) {
  constexpr int MT = (BM / WM) / 16;   // acc tiles per wave, m dim
  constexpr int NT = (BN / WN) / 16;   // acc tiles per wave, n dim
  constexpr int AI = BM / 128;         // A gld16 issues per wave per k-tile
  constexpr int BI = BN / 128;         // B gld16 issues per wave per k-tile
  constexpr int PW = AI + BI;          // this wave's loads per k-tile
  __shared__ alignas(16) uint16_t As[4][BM * 32];
  __shared__ alignas(16) uint16_t Bs[4][BN * 32];

  const int tid = threadIdx.x;
  const int w = tid >> 6, lane = tid & 63;
  const int wm = w / WN, wn = w % WN;

  // bijective XCD chunk swizzle (m204): consecutive logical tiles -> same XCD
  // L2. All grids here have nwg % 8 == 0.
  const int gx = gridDim.x, gy = gridDim.y;
  const int nwg = gx * gy * gridDim.z;
  const int hw = blockIdx.x + gx * (blockIdx.y + gy * blockIdx.z);
  const int lg = (hw & 7) * (nwg >> 3) + (hw >> 3);
  const int bx = lg % gx, byz = lg / gx;
  const int by = byz % gy, z = byz / gy;

  const int m0 = by * BM, n0 = bx * BN;

  const uint16_t* Ab = A;
  const uint16_t* Bb = Bt;
  if (MODE == 1) { Ab += (size_t)z * 2048 * 512;  Bb += (size_t)z * 2048 * 512; }
  if (MODE == 2) { Ab += (size_t)z * 2048 * 2048; Bb += (size_t)z * 512 * 2048; }

  // staging: one wave-wide gld16 covers 16 rows x 32 k (1024B linear LDS).
  // k-chunk XOR swizzle kept from R7 (neutral; reads un-permute with swz).
  const int kc = (((lane & 3) ^ ((lane >> 2) & 3) ^ (lane >> 4)) * 8);
  const int rbA = w * (BM / 8);             // this wave's A row base
  const int rbB = w * (BN / 8);             // this wave's B row base
  const uint16_t* gA = Ab + (size_t)(m0 + rbA + (lane >> 2)) * lda + kc;
  const uint16_t* gB = Bb + (size_t)(n0 + rbB + (lane >> 2)) * ldb + kc;

  f32x4 acc[MT][NT];
#pragma unroll
  for (int i = 0; i < MT; i++)
#pragma unroll
    for (int j = 0; j < NT; j++) acc[i][j] = (f32x4){0.f, 0.f, 0.f, 0.f};

  const int lr = lane & 15;
  const int swz = (((lane >> 4) ^ (lr & 3) ^ (lr >> 2)) * 8);
  const int iters = K >> 5;

  auto stage = [&](int t, int buf) {
    const int k0 = t * 32;
#pragma unroll
    for (int j = 0; j < AI; j++)
      gld16(gA + k0 + (size_t)(j * 16) * lda, &As[buf][(rbA + j * 16) * 32]);
#pragma unroll
    for (int j = 0; j < BI; j++)
      gld16(gB + k0 + (size_t)(j * 16) * ldb, &Bs[buf][(rbB + j * 16) * 32]);
  };

  auto compute = [&](int buf) {
    bf16x8 af[MT], bfr[NT];
#pragma unroll
    for (int t = 0; t < MT; t++)
      af[t] = *(const bf16x8*)&As[buf][(wm * (BM / WM) + t * 16 + lr) * 32 + swz];
#pragma unroll
    for (int t = 0; t < NT; t++)
      bfr[t] = *(const bf16x8*)&Bs[buf][(wn * (BN / WN) + t * 16 + lr) * 32 + swz];
#pragma unroll
    for (int nt = 0; nt < NT; nt++)
#pragma unroll
      for (int mt = 0; mt < MT; mt++)
        acc[mt][nt] = __builtin_amdgcn_mfma_f32_16x16x32_bf16(
            af[mt], bfr[nt], acc[mt][nt], 0, 0, 0);
  };

  // ---- depth-3 pipelined K-loop: 4 buffers, 1 barrier/iter, up to 3 tiles
  // of loads in flight; vmcnt counted (2*PW mid-loop), never 0 till the end.
  // iter i: wait so tile i's loads are done (leave i+1, i+2 in flight)
  //         barrier   [tile i visible; buf (i-1)&3 consumers all done]
  //         stage(i+3, (i+3)&3)   [= buf (i-1)&3, freed by the barrier]
  //         compute(i&3)
  stage(0, 0);
  stage(1, 1);
  stage(2, 2);
  for (int i = 0; i < iters; ++i) {
    if (i + 2 < iters) {
      asm volatile("s_waitcnt vmcnt(%0)" ::"i"(2 * PW) : "memory");
    } else if (i + 1 < iters) {
      asm volatile("s_waitcnt vmcnt(%0)" ::"i"(PW) : "memory");
    } else {
      asm volatile("s_waitcnt vmcnt(0)" ::: "memory");
    }
    __builtin_amdgcn_s_barrier();
    if (i + 3 < iters) stage(i + 3, (i + 3) & 3);
    compute(i & 3);
  }

  // epilogue: C/D layout col=lane&15, row=quad*4+reg  (m89/m91 verified)
  if (MODE == 1) {
    uint16_t* Sp = (uint16_t*)OutA + (size_t)z * 2048 * 2048;
#pragma unroll
    for (int mt = 0; mt < MT; mt++) {
      float rp[4] = {0.f, 0.f, 0.f, 0.f};
#pragma unroll
      for (int nt = 0; nt < NT; nt++) {
#pragma unroll
        for (int i = 0; i < 4; i++) {
          const int row = m0 + wm * (BM / WM) + mt * 16 + (lane >> 4) * 4 + i;
          const int col = n0 + wn * (BN / WN) + nt * 16 + lr;
          const float e = __expf(acc[mt][nt][i] * scale);
          Sp[(size_t)row * 2048 + col] = f2bf(e);
          rp[i] += e;
        }
      }
#pragma unroll
      for (int i = 0; i < 4; i++) {
        float p = rp[i];
        p += __shfl_xor(p, 1); p += __shfl_xor(p, 2);
        p += __shfl_xor(p, 4); p += __shfl_xor(p, 8);
        if (lr == 0) {
          const int row = m0 + wm * (BM / WM) + mt * 16 + (lane >> 4) * 4 + i;
          atomicAdd(&rsum[z * 2048 + row], p);
        }
      }
    }
  } else if (MODE == 2) {
#pragma unroll
    for (int mt = 0; mt < MT; mt++) {
#pragma unroll
      for (int i = 0; i < 4; i++) {
        const int row = m0 + wm * (BM / WM) + mt * 16 + (lane >> 4) * 4 + i;
        const float sc = 1.0f / rsum[z * 2048 + row];
#pragma unroll
        for (int nt = 0; nt < NT; nt++) {
          const int col = n0 + wn * (BN / WN) + nt * 16 + lr;
          ((uint16_t*)OutA)[((size_t)z * 2048 + row) * 512 + col] =
              f2bf(acc[mt][nt][i] * sc);
        }
      }
    }
  } else {
#pragma unroll
    for (int mt = 0; mt < MT; mt++) {
#pragma unroll
      for (int nt = 0; nt < NT; nt++) {
#pragma unroll
        for (int i = 0; i < 4; i++) {
          const int row = m0 + wm * (BM / WM) + mt * 16 + (lane >> 4) * 4 + i;
          const int col = n0 + wn * (BN / WN) + nt * 16 + lr;
          const float v = acc[mt][nt][i];
          if (MODE == 0) {
            const int which = col >> 9, c = col & 511;
            if (which == 0) {
              ((uint16_t*)OutA)[(size_t)row * 512 + c] = f2bf(v + b0[c]);
            } else if (which == 1) {
              OutK[(size_t)row * 512 + c] = f2bf(v + b1[c]);
            } else {  // v -> transposed vT[b][h][t]
              OutVT[(size_t)(row >> 11) * (512 * 2048) + (size_t)c * 2048 +
                    (row & 2047)] = f2bf(v + b2[c]);
            }
          } else {  // MODE 3
            const size_t idx = (size_t)row * 512 + col;
            ((float*)OutA)[idx] = v + b0[col] + Xres[idx];
          }
        }
      }
    }
  }
}

// Fused conversions: X fp32->bf16 (8.39M elems, 4/thread), Wt transpose
// (first 1.05M threads), rowsum zeroing (first 16384 threads).
__global__ __launch_bounds__(256) void cvt_all_k(
    const float* __restrict__ X, uint16_t* __restrict__ Xb,
    const float* __restrict__ Wq, const float* __restrict__ Wk,
    const float* __restrict__ Wv, const float* __restrict__ Wo,
    uint16_t* __restrict__ Wt, float* __restrict__ rsum) {
  const int i = blockIdx.x * 256 + threadIdx.x;   // 0..2097151
  const float4 f = ((const float4*)X)[i];
  uint32_t lo = (uint32_t)f2bf(f.x) | ((uint32_t)f2bf(f.y) << 16);
  uint32_t hi = (uint32_t)f2bf(f.z) | ((uint32_t)f2bf(f.w) << 16);
  ((uint2*)Xb)[i] = make_uint2(lo, hi);
  if (i < 16384) rsum[i] = 0.f;
  if (i < 2048 * 512) {   // Wt[n][k] = W[k][n&511]
    const int n = i >> 9, kk = i & 511;
    const int which = n >> 9, c = n & 511;
    const float* W =
        (which == 0) ? Wq : (which == 1) ? Wk : (which == 2) ? Wv : Wo;
    Wt[i] = f2bf(W[kk * 512 + c]);
  }
}

// in-place layernorm, wave per row of 512 fp32
__global__ __launch_bounds__(256) void ln_k(float* __restrict__ O,
                                            const float* __restrict__ g,
                                            const float* __restrict__ b) {
  const int tid = threadIdx.x, w = tid >> 6, lane = tid & 63;
  float* p = O + ((size_t)blockIdx.x * 4 + w) * 512;
  float4 v0 = ((const float4*)p)[lane];
  float4 v1 = ((const float4*)p)[64 + lane];
  float s  = v0.x + v0.y + v0.z + v0.w + v1.x + v1.y + v1.z + v1.w;
  float sq = v0.x * v0.x + v0.y * v0.y + v0.z * v0.z + v0.w * v0.w +
             v1.x * v1.x + v1.y * v1.y + v1.z * v1.z + v1.w * v1.w;
#pragma unroll
  for (int off = 32; off >= 1; off >>= 1) {
    s += __shfl_xor(s, off);
    sq += __shfl_xor(sq, off);
  }
  const float mean = s * (1.f / 512.f);
  const float var = sq * (1.f / 512.f) - mean * mean;  // population var (jnp.var)
  const float rstd = rsqrtf(var + 1e-5f);
  const float4 g0 = ((const float4*)g)[lane], g1 = ((const float4*)g)[64 + lane];
  const float4 b0 = ((const float4*)b)[lane], b1 = ((const float4*)b)[64 + lane];
  v0.x = (v0.x - mean) * rstd * g0.x + b0.x;
  v0.y = (v0.y - mean) * rstd * g0.y + b0.y;
  v0.z = (v0.z - mean) * rstd * g0.z + b0.z;
  v0.w = (v0.w - mean) * rstd * g0.w + b0.w;
  v1.x = (v1.x - mean) * rstd * g1.x + b1.x;
  v1.y = (v1.y - mean) * rstd * g1.y + b1.y;
  v1.z = (v1.z - mean) * rstd * g1.z + b1.z;
  v1.w = (v1.w - mean) * rstd * g1.w + b1.w;
  ((float4*)p)[lane] = v0;
  ((float4*)p)[64 + lane] = v1;
}

extern "C" void kernel_launch(void* const* d_in, const int* in_sizes, int n_in,
                              void* d_out, int out_size, void* d_ws,
                              size_t ws_size, hipStream_t stream) {
  const float* X     = (const float*)d_in[0];
  const float* Wq    = (const float*)d_in[1];
  const float* bq    = (const float*)d_in[2];
  const float* Wk    = (const float*)d_in[3];
  const float* bk    = (const float*)d_in[4];
  const float* Wv    = (const float*)d_in[5];
  const float* bv    = (const float*)d_in[6];
  const float* Wo    = (const float*)d_in[7];
  const float* bo    = (const float*)d_in[8];
  const float* gamma = (const float*)d_in[9];
  const float* beta  = (const float*)d_in[10];
  float* out = (float*)d_out;

  char* ws = (char*)d_ws;   // ~114.1 MB used (overlaid layout, see header)
  uint16_t* S    = (uint16_t*)(ws);                 // [0, 64M)
  uint16_t* Xb   = (uint16_t*)(ws);                 // [0, 16M) overlay on S
  uint16_t* Wt   = (uint16_t*)(ws + 67108864);      // [64M, 66M)
  uint16_t* q    = (uint16_t*)(ws + 69206016);      // [66M, 82M), later ctx
  uint16_t* kb   = (uint16_t*)(ws + 85983232);      // [82M, 98M)
  uint16_t* vT   = (uint16_t*)(ws + 102760448);     // [98M, 114M) [8][512][2048]
  float*    rsum = (float*)(ws + 119537664);        // [114M, +64K) fp32[16384]
  uint16_t* ctx  = q;                               // overlay: q dead after scores

  cvt_all_k<<<dim3(8192), dim3(256), 0, stream>>>(X, Xb, Wq, Wk, Wv, Wo, Wt,
                                                  rsum);
  // QKV: M=16384, N=1536, K=512, tile 128x128 (1536 blocks)
  gemm_k<0, 128, 128, 2, 4><<<dim3(12, 128, 1), dim3(512), 0, stream>>>(
      Xb, Wt, (void*)q, kb, vT, nullptr, 512, 512, 512, bq, bk, bv, nullptr,
      1.f);
  // scores: per batch M=N=2048, K=512; tile 128x128 (2048 blocks)
  gemm_k<1, 128, 128, 2, 4><<<dim3(16, 16, 8), dim3(512), 0, stream>>>(
      q, kb, (void*)S, nullptr, nullptr, rsum, 512, 512, 512, nullptr, nullptr,
      nullptr, nullptr, 0.044194173824159216f);
  // ctx = (E @ V)/rowsum: per batch M=2048, N=512, K=2048, tile 128x128
  gemm_k<2, 128, 128, 2, 4><<<dim3(4, 16, 8), dim3(512), 0, stream>>>(
      S, vT, (void*)ctx, nullptr, nullptr, rsum, 2048, 2048, 2048, nullptr,
      nullptr, nullptr, nullptr, 1.f);
  // out = ctx @ Wo + bo + X: M=16384, N=512, K=512, tile 128x128
  gemm_k<3, 128, 128, 2, 4><<<dim3(4, 128, 1), dim3(512), 0, stream>>>(
      ctx, Wt + 1536 * 512, (void*)out, nullptr, nullptr, nullptr, 512, 512,
      512, bo, nullptr, nullptr, X, 1.f);
  ln_k<<<dim3(4096), dim3(256), 0, stream>>>(out, gamma, beta);
}

// Round 6
// 337.560 us; speedup vs baseline: 1.0709x; 1.0709x over previous
//
#include <hip/hip_runtime.h>
#include <cstdint>
#include <cstddef>

// ============================================================================
// CellSetAttentionNetwork: X[8,2048,512] fp32, single-head attention D=H=512.
// Pipeline: cvt(all) -> QKV gemm -> scores gemm (exp + rowsum fused) ->
//           PV gemm (1/rowsum fused) -> out gemm -> layernorm.
// R12: phase-interleaved counted-vmcnt GEMM engine (T2+T3+T4+T5 port).
// R6-R11 established: the 2-barrier depth-N structure is ceiling-locked at
// ~460 TF (MfmaUtil 12%) regardless of depth/occupancy/tile knobs - the
// documented m233 regime (stage+vmcnt+barrier = critical path). This is the
// 8-phase-class rewrite:
//  - 256x128 tile, 8 waves (wave tile 64x64), BK=64, THREE K-tile LDS
//    buffers (144KB): staging lead = 4 phases (~700cy, covers L3 latency),
//    mid-loop s_waitcnt vmcnt(6) NEVER drains (T4; m218: counted-vmcnt IS
//    the gain).
//  - 2 phases per K-tile (row-half x full cols): each phase =
//    {12 ds_read_b128 || 3 global_load_lds -> barrier -> setprio(1) ->
//     16 MFMA -> setprio(0) -> barrier}  (HK per-phase composition).
//  - T2 swizzle, correct BK=64 geometry: [row][64elem] rows are 128B ->
//    16-way ds_read conflict; store k-chunk c XOR (row&7). global_load_lds
//    writes linearly, so the permutation is applied to the per-lane GLOBAL
//    chunk ((l&7)^(l>>3); every 8-lane group still covers one full 128B row
//    -> coalescing intact) and un-applied on the fragment read (rule #21).
// Softmax max-free: scores stores E=exp(s*scale)+rowsum atomics; PV divides.
//
// ws layout (byte offsets):
//   [0, 64M)      S/E [8][2048][2048] bf16
//   [0, 16M)      Xb  [16384][512] bf16 (overlay: dead before S written)
//   [64M, +2M)    Wt  [2048][512] bf16 (Wq^T,Wk^T,Wv^T,Wo^T stacked)
//   [66M, +16M)   q   [16384][512] bf16; reused as ctx after scores gemm
//   [82M, +16M)   k   [16384][512] bf16
//   [98M, +16M)   vT  [8][512][2048] bf16
//   [114M, +64K)  rowsum fp32[16384]
// ============================================================================

typedef __bf16 bf16x8 __attribute__((ext_vector_type(8)));
typedef float  f32x4  __attribute__((ext_vector_type(4)));

__device__ __forceinline__ uint16_t f2bf(float f) {
  union { float f; uint32_t u; } v; v.f = f;
  uint32_t r = v.u + 0x7FFFu + ((v.u >> 16) & 1u);   // RNE
  return (uint16_t)(r >> 16);
}

__device__ __forceinline__ void gld16(const uint16_t* g, uint16_t* l) {
  // async global->LDS, 16B per lane; LDS dest = wave-uniform base + lane*16
  __builtin_amdgcn_global_load_lds(
      (__attribute__((address_space(1))) void*)(g),
      (__attribute__((address_space(3))) void*)(l), 16, 0, 0);
}

// MODE 0: QKV   (out q, k normal [M][512]; v transposed vT[b][h][t], +bias)
// MODE 1: scores (out bf16 E=exp(s*scale), rowsum atomics), batch = z
// MODE 2: ctx = (E @ vT^T)/rowsum  (out bf16 [b*2048+n][512]), batch = z
// MODE 3: out-proj (+bo +X residual, fp32 out)
// Fixed geometry: BM=256, BN=128, 8 waves 4x2, wave tile 64x64, BK=64,
// K % 128 == 0, K/64 >= 2.
template <int MODE, int BM, int BN, int WM, int WN>
__global__ __launch_bounds__(512, 2) void gemm_k(
    const uint16_t* __restrict__ A, const uint16_t* __restrict__ Bt,
    void* __restrict__ OutA, uint16_t* __restrict__ OutK,
    uint16_t* __restrict__ OutVT, float* __restrict__ rsum, int K, int lda,
    int ldb, const float* __restrict__ b0, const float* __restrict__ b1,
    const float* __restrict__ b2, const float* __restrict__ Xres, float scale) {
  constexpr int WR = BM / WM;          // 64 rows per wave
  constexpr int WC = BN / WN;          // 64 cols per wave
  constexpr int MT = WR / 16;          // 4 acc tiles, m
  constexpr int NT = WC / 16;          // 4 acc tiles, n
  constexpr int SA = BM / 64;          // 4 A gld16 units per wave per K-tile
  constexpr int SB = BN / 64;          // 2 B gld16 units per wave per K-tile
  static_assert(WR == 64 && WC == 64 && SA == 4 && SB == 2, "geometry");
  __shared__ alignas(16) uint16_t As[3][BM * 64];   // 96 KB
  __shared__ alignas(16) uint16_t Bs[3][BN * 64];   // 48 KB

  const int tid = threadIdx.x;
  const int w = tid >> 6, lane = tid & 63;
  const int wm = w / WN, wn = w % WN;

  // bijective XCD chunk swizzle (m204): consecutive logical tiles -> same XCD
  // L2. All grids here have nwg % 8 == 0.
  const int gx = gridDim.x, gy = gridDim.y;
  const int nwg = gx * gy * gridDim.z;
  const int hw = blockIdx.x + gx * (blockIdx.y + gy * blockIdx.z);
  const int lg = (hw & 7) * (nwg >> 3) + (hw >> 3);
  const int bx = lg % gx, byz = lg / gx;
  const int by = byz % gy, z = byz / gy;

  const int m0 = by * BM, n0 = bx * BN;

  const uint16_t* Ab = A;
  const uint16_t* Bb = Bt;
  if (MODE == 1) { Ab += (size_t)z * 2048 * 512;  Bb += (size_t)z * 2048 * 512; }
  if (MODE == 2) { Ab += (size_t)z * 2048 * 2048; Bb += (size_t)z * 512 * 2048; }

  // ---- staging (T2 both-sides swizzle) ----
  // LDS layout per buffer: [row][64] elems, but the 8 16B k-chunks of each
  // row are stored permuted: slot s holds logical chunk s ^ (row&7).
  // gld16 writes linearly (lane l -> row base+ l>>3, slot l&7), so lane l
  // FETCHES global chunk (l&7)^(l>>3). 8-lane groups cover a full 128B row.
  const int l3 = lane >> 3, l7 = lane & 7;
  const int csw = (l7 ^ l3) * 8;
  const uint16_t* gAb = Ab + (size_t)(m0 + w * 8 + l3) * lda + csw;
  const uint16_t* gBb = Bb + (size_t)(n0 + w * 8 + l3) * ldb + csw;
  const int ldsw = w * 512;            // elems: wave's 8-row slice in a unit

  // unit v covers rows [v*64, v*64+64) of the operand tile
  auto stageA = [&](int v, int bufb, int kg) {
    gld16(gAb + (size_t)(v * 64) * lda + kg, &As[bufb][v * 4096 + ldsw]);
  };
  auto stageB = [&](int v, int bufb, int kg) {
    gld16(gBb + (size_t)(v * 64) * ldb + kg, &Bs[bufb][v * 4096 + ldsw]);
  };

  f32x4 acc[MT][NT];
#pragma unroll
  for (int i = 0; i < MT; i++)
#pragma unroll
    for (int j = 0; j < NT; j++) acc[i][j] = (f32x4){0.f, 0.f, 0.f, 0.f};

  const int lr = lane & 15, q4 = lane >> 4;
  // fragment read: un-permute chunk: slot = (ks*4 + q4) ^ (row&7), row&7==l7
  const int rc0 = ((q4) ^ l7) * 8;       // ks = 0  (k 0..31)
  const int rc1 = ((4 + q4) ^ l7) * 8;   // ks = 1  (k 32..63)

  const int NK = K >> 6;

  // ---- prologue: stage K-tiles 0,1; wait for tile 0 (6 stay in flight) ----
#pragma unroll
  for (int u = 0; u < SA; u++) stageA(u, 0, 0);
#pragma unroll
  for (int u = 0; u < SB; u++) stageB(u, 0, 0);
#pragma unroll
  for (int u = 0; u < SA; u++) stageA(u, 1, 64);
#pragma unroll
  for (int u = 0; u < SB; u++) stageB(u, 1, 64);
  asm volatile("s_waitcnt vmcnt(6)" ::: "memory");
  __builtin_amdgcn_s_barrier();

  // ---- main loop: per K-tile kt, 2 phases (row-half QM x full cols) ----
  // phase = {12 ds_read_b128 | 3 gld16 of kt+2 -> barrier -> setprio(1) ->
  //          16 MFMA -> setprio(0) [-> counted vmcnt] -> barrier}
#define QPHASE(QM, S0, S1, S2, DRAIN)                                          \
  {                                                                            \
    bf16x8 af0[2], af1[2], bv0[4], bv1[4];                                     \
    _Pragma("unroll") for (int t = 0; t < 2; t++) {                            \
      const int ra = (wm * 64 + (QM) * 32 + t * 16 + lr) * 64;                 \
      af0[t] = *(const bf16x8*)&As[cb][ra + rc0];                              \
      af1[t] = *(const bf16x8*)&As[cb][ra + rc1];                              \
    }                                                                          \
    _Pragma("unroll") for (int t = 0; t < 4; t++) {                            \
      const int rb = (wn * 64 + t * 16 + lr) * 64;                             \
      bv0[t] = *(const bf16x8*)&Bs[cb][rb + rc0];                              \
      bv1[t] = *(const bf16x8*)&Bs[cb][rb + rc1];                              \
    }                                                                          \
    if (st) { S0; S1; S2; }                                                    \
    __builtin_amdgcn_s_barrier();                                              \
    __builtin_amdgcn_s_setprio(1);                                             \
    _Pragma("unroll") for (int nt = 0; nt < 4; nt++)                           \
      _Pragma("unroll") for (int mt = 0; mt < 2; mt++)                         \
        acc[(QM) * 2 + mt][nt] = __builtin_amdgcn_mfma_f32_16x16x32_bf16(      \
            af0[mt], bv0[nt], acc[(QM) * 2 + mt][nt], 0, 0, 0);                \
    _Pragma("unroll") for (int nt = 0; nt < 4; nt++)                           \
      _Pragma("unroll") for (int mt = 0; mt < 2; mt++)                         \
        acc[(QM) * 2 + mt][nt] = __builtin_amdgcn_mfma_f32_16x16x32_bf16(      \
            af1[mt], bv1[nt], acc[(QM) * 2 + mt][nt], 0, 0, 0);                \
    __builtin_amdgcn_s_setprio(0);                                             \
    DRAIN;                                                                     \
    __builtin_amdgcn_s_barrier();                                              \
  }

  for (int kt = 0; kt < NK; ++kt) {
    const int cb = kt % 3;               // buffer being computed
    const int sbuf = (kt + 2) % 3;       // buffer being staged (== (kt-1)%3,
                                         // freed by previous group's barrier)
    const bool st = (kt + 2) < NK;
    const int kg = (kt + 2) << 6;
    QPHASE(0, stageA(0, sbuf, kg), stageA(1, sbuf, kg), stageA(2, sbuf, kg), )
    QPHASE(1, stageA(3, sbuf, kg), stageB(0, sbuf, kg), stageB(1, sbuf, kg),
           if (kt + 1 < NK) {
             if (st) { asm volatile("s_waitcnt vmcnt(6)" ::: "memory"); }
             else    { asm volatile("s_waitcnt vmcnt(0)" ::: "memory"); }
           })
  }
#undef QPHASE

  // epilogue: C/D layout col=lane&15, row=quad*4+reg  (m89/m91 verified)
  if (MODE == 1) {
    uint16_t* Sp = (uint16_t*)OutA + (size_t)z * 2048 * 2048;
#pragma unroll
    for (int mt = 0; mt < MT; mt++) {
      float rp[4] = {0.f, 0.f, 0.f, 0.f};
#pragma unroll
      for (int nt = 0; nt < NT; nt++) {
#pragma unroll
        for (int i = 0; i < 4; i++) {
          const int row = m0 + wm * WR + mt * 16 + (lane >> 4) * 4 + i;
          const int col = n0 + wn * WC + nt * 16 + lr;
          const float e = __expf(acc[mt][nt][i] * scale);
          Sp[(size_t)row * 2048 + col] = f2bf(e);
          rp[i] += e;
        }
      }
#pragma unroll
      for (int i = 0; i < 4; i++) {
        float p = rp[i];
        p += __shfl_xor(p, 1); p += __shfl_xor(p, 2);
        p += __shfl_xor(p, 4); p += __shfl_xor(p, 8);
        if (lr == 0) {
          const int row = m0 + wm * WR + mt * 16 + (lane >> 4) * 4 + i;
          atomicAdd(&rsum[z * 2048 + row], p);
        }
      }
    }
  } else if (MODE == 2) {
#pragma unroll
    for (int mt = 0; mt < MT; mt++) {
#pragma unroll
      for (int i = 0; i < 4; i++) {
        const int row = m0 + wm * WR + mt * 16 + (lane >> 4) * 4 + i;
        const float sc = 1.0f / rsum[z * 2048 + row];
#pragma unroll
        for (int nt = 0; nt < NT; nt++) {
          const int col = n0 + wn * WC + nt * 16 + lr;
          ((uint16_t*)OutA)[((size_t)z * 2048 + row) * 512 + col] =
              f2bf(acc[mt][nt][i] * sc);
        }
      }
    }
  } else {
#pragma unroll
    for (int mt = 0; mt < MT; mt++) {
#pragma unroll
      for (int nt = 0; nt < NT; nt++) {
#pragma unroll
        for (int i = 0; i < 4; i++) {
          const int row = m0 + wm * WR + mt * 16 + (lane >> 4) * 4 + i;
          const int col = n0 + wn * WC + nt * 16 + lr;
          const float v = acc[mt][nt][i];
          if (MODE == 0) {
            const int which = col >> 9, c = col & 511;
            if (which == 0) {
              ((uint16_t*)OutA)[(size_t)row * 512 + c] = f2bf(v + b0[c]);
            } else if (which == 1) {
              OutK[(size_t)row * 512 + c] = f2bf(v + b1[c]);
            } else {  // v -> transposed vT[b][h][t]
              OutVT[(size_t)(row >> 11) * (512 * 2048) + (size_t)c * 2048 +
                    (row & 2047)] = f2bf(v + b2[c]);
            }
          } else {  // MODE 3
            const size_t idx = (size_t)row * 512 + col;
            ((float*)OutA)[idx] = v + b0[col] + Xres[idx];
          }
        }
      }
    }
  }
}

// Fused conversions: X fp32->bf16 (8.39M elems, 4/thread), Wt transpose
// (first 1.05M threads), rowsum zeroing (first 16384 threads).
__global__ __launch_bounds__(256) void cvt_all_k(
    const float* __restrict__ X, uint16_t* __restrict__ Xb,
    const float* __restrict__ Wq, const float* __restrict__ Wk,
    const float* __restrict__ Wv, const float* __restrict__ Wo,
    uint16_t* __restrict__ Wt, float* __restrict__ rsum) {
  const int i = blockIdx.x * 256 + threadIdx.x;   // 0..2097151
  const float4 f = ((const float4*)X)[i];
  uint32_t lo = (uint32_t)f2bf(f.x) | ((uint32_t)f2bf(f.y) << 16);
  uint32_t hi = (uint32_t)f2bf(f.z) | ((uint32_t)f2bf(f.w) << 16);
  ((uint2*)Xb)[i] = make_uint2(lo, hi);
  if (i < 16384) rsum[i] = 0.f;
  if (i < 2048 * 512) {   // Wt[n][k] = W[k][n&511]
    const int n = i >> 9, kk = i & 511;
    const int which = n >> 9, c = n & 511;
    const float* W =
        (which == 0) ? Wq : (which == 1) ? Wk : (which == 2) ? Wv : Wo;
    Wt[i] = f2bf(W[kk * 512 + c]);
  }
}

// in-place layernorm, wave per row of 512 fp32
__global__ __launch_bounds__(256) void ln_k(float* __restrict__ O,
                                            const float* __restrict__ g,
                                            const float* __restrict__ b) {
  const int tid = threadIdx.x, w = tid >> 6, lane = tid & 63;
  float* p = O + ((size_t)blockIdx.x * 4 + w) * 512;
  float4 v0 = ((const float4*)p)[lane];
  float4 v1 = ((const float4*)p)[64 + lane];
  float s  = v0.x + v0.y + v0.z + v0.w + v1.x + v1.y + v1.z + v1.w;
  float sq = v0.x * v0.x + v0.y * v0.y + v0.z * v0.z + v0.w * v0.w +
             v1.x * v1.x + v1.y * v1.y + v1.z * v1.z + v1.w * v1.w;
#pragma unroll
  for (int off = 32; off >= 1; off >>= 1) {
    s += __shfl_xor(s, off);
    sq += __shfl_xor(sq, off);
  }
  const float mean = s * (1.f / 512.f);
  const float var = sq * (1.f / 512.f) - mean * mean;  // population var (jnp.var)
  const float rstd = rsqrtf(var + 1e-5f);
  const float4 g0 = ((const float4*)g)[lane], g1 = ((const float4*)g)[64 + lane];
  const float4 b0 = ((const float4*)b)[lane], b1 = ((const float4*)b)[64 + lane];
  v0.x = (v0.x - mean) * rstd * g0.x + b0.x;
  v0.y = (v0.y - mean) * rstd * g0.y + b0.y;
  v0.z = (v0.z - mean) * rstd * g0.z + b0.z;
  v0.w = (v0.w - mean) * rstd * g0.w + b0.w;
  v1.x = (v1.x - mean) * rstd * g1.x + b1.x;
  v1.y = (v1.y - mean) * rstd * g1.y + b1.y;
  v1.z = (v1.z - mean) * rstd * g1.z + b1.z;
  v1.w = (v1.w - mean) * rstd * g1.w + b1.w;
  ((float4*)p)[lane] = v0;
  ((float4*)p)[64 + lane] = v1;
}

extern "C" void kernel_launch(void* const* d_in, const int* in_sizes, int n_in,
                              void* d_out, int out_size, void* d_ws,
                              size_t ws_size, hipStream_t stream) {
  const float* X     = (const float*)d_in[0];
  const float* Wq    = (const float*)d_in[1];
  const float* bq    = (const float*)d_in[2];
  const float* Wk    = (const float*)d_in[3];
  const float* bk    = (const float*)d_in[4];
  const float* Wv    = (const float*)d_in[5];
  const float* bv    = (const float*)d_in[6];
  const float* Wo    = (const float*)d_in[7];
  const float* bo    = (const float*)d_in[8];
  const float* gamma = (const float*)d_in[9];
  const float* beta  = (const float*)d_in[10];
  float* out = (float*)d_out;

  char* ws = (char*)d_ws;   // ~114.1 MB used (overlaid layout, see header)
  uint16_t* S    = (uint16_t*)(ws);                 // [0, 64M)
  uint16_t* Xb   = (uint16_t*)(ws);                 // [0, 16M) overlay on S
  uint16_t* Wt   = (uint16_t*)(ws + 67108864);      // [64M, 66M)
  uint16_t* q    = (uint16_t*)(ws + 69206016);      // [66M, 82M), later ctx
  uint16_t* kb   = (uint16_t*)(ws + 85983232);      // [82M, 98M)
  uint16_t* vT   = (uint16_t*)(ws + 102760448);     // [98M, 114M) [8][512][2048]
  float*    rsum = (float*)(ws + 119537664);        // [114M, +64K) fp32[16384]
  uint16_t* ctx  = q;                               // overlay: q dead after scores

  cvt_all_k<<<dim3(8192), dim3(256), 0, stream>>>(X, Xb, Wq, Wk, Wv, Wo, Wt,
                                                  rsum);
  // QKV: M=16384, N=1536, K=512, tile 256x128 (768 blocks)
  gemm_k<0, 256, 128, 4, 2><<<dim3(12, 64, 1), dim3(512), 0, stream>>>(
      Xb, Wt, (void*)q, kb, vT, nullptr, 512, 512, 512, bq, bk, bv, nullptr,
      1.f);
  // scores: per batch M=N=2048, K=512; tile 256x128 (1024 blocks)
  gemm_k<1, 256, 128, 4, 2><<<dim3(16, 8, 8), dim3(512), 0, stream>>>(
      q, kb, (void*)S, nullptr, nullptr, rsum, 512, 512, 512, nullptr, nullptr,
      nullptr, nullptr, 0.044194173824159216f);
  // ctx = (E @ V)/rowsum: per batch M=2048, N=512, K=2048, tile 256x128
  gemm_k<2, 256, 128, 4, 2><<<dim3(4, 8, 8), dim3(512), 0, stream>>>(
      S, vT, (void*)ctx, nullptr, nullptr, rsum, 2048, 2048, 2048, nullptr,
      nullptr, nullptr, nullptr, 1.f);
  // out = ctx @ Wo + bo + X: M=16384, N=512, K=512, tile 256x128
  gemm_k<3, 256, 128, 4, 2><<<dim3(4, 64, 1), dim3(512), 0, stream>>>(
      ctx, Wt + 1536 * 512, (void*)out, nullptr, nullptr, nullptr, 512, 512,
      512, bo, nullptr, nullptr, X, 1.f);
  ln_k<<<dim3(4096), dim3(256), 0, stream>>>(out, gamma, beta);
}

// Round 7
// 316.813 us; speedup vs baseline: 1.1410x; 1.0655x over previous
//
#include <hip/hip_runtime.h>
#include <cstdint>
#include <cstddef>

// ============================================================================
// CellSetAttentionNetwork: X[8,2048,512] fp32, single-head attention D=H=512.
// Pipeline: cvt(all) -> QKV gemm -> scores gemm (exp + rowsum fused) ->
//           PV gemm (1/rowsum fused) -> fused out-proj+residual+LayerNorm.
// R13: revert GEMM engine to the R10-proven template (best total 317.6us;
// R12's phase-split port hit 0 bank conflicts yet lost 24us/dispatch ->
// conflicts off critical path, m252 confirmed; 144KB LDS = 1 blk/CU killed
// it). Spend the round on certain byte/dispatch removal instead:
//   MODE 4 = out-proj + bo + X residual + LayerNorm fused, BM=64 x BN=512
//   (block owns full rows; LN stats via 4KB LDS cross-wave reduce).
//   Deletes ln_k dispatch + 67MB fp32 out round-trip + 3/4 of ctx restaging.
//   BM=64: A staging is 4 wave-issues; waves 4-7 redundantly re-stage A
//   (same bytes+dest) so per-wave vmcnt(PW) stays uniform.
// K-loop: R7/R10-proven depth-2, 3 buffers, ONE barrier/iter, vmcnt(PW)
// never 0 mid-loop. XCD chunk swizzle kept (FETCH 68.7->21.7MB proven).
// Softmax max-free: scores stores E=exp(s*scale)+rowsum atomics; PV divides.
//
// ws layout (byte offsets):
//   [0, 64M)      S/E [8][2048][2048] bf16
//   [0, 16M)      Xb  [16384][512] bf16 (overlay: dead before S written)
//   [64M, +2M)    Wt  [2048][512] bf16 (Wq^T,Wk^T,Wv^T,Wo^T stacked)
//   [66M, +16M)   q   [16384][512] bf16; reused as ctx after scores gemm
//   [82M, +16M)   k   [16384][512] bf16
//   [98M, +16M)   vT  [8][512][2048] bf16
//   [114M, +64K)  rowsum fp32[16384]
// ============================================================================

typedef __bf16 bf16x8 __attribute__((ext_vector_type(8)));
typedef float  f32x4  __attribute__((ext_vector_type(4)));

__device__ __forceinline__ uint16_t f2bf(float f) {
  union { float f; uint32_t u; } v; v.f = f;
  uint32_t r = v.u + 0x7FFFu + ((v.u >> 16) & 1u);   // RNE
  return (uint16_t)(r >> 16);
}

__device__ __forceinline__ void gld16(const uint16_t* g, uint16_t* l) {
  // async global->LDS, 16B per lane; LDS dest = wave-uniform base + lane*16
  __builtin_amdgcn_global_load_lds(
      (__attribute__((address_space(1))) void*)(g),
      (__attribute__((address_space(3))) void*)(l), 16, 0, 0);
}

// MODE 0: QKV   (out q, k normal [M][512]; v transposed vT[b][h][t], +bias)
// MODE 1: scores (out bf16 E=exp(s*scale), rowsum atomics), batch = z
// MODE 2: ctx = (E @ vT^T)/rowsum  (out bf16 [b*2048+n][512]), batch = z
// MODE 4: out-proj + b0 + Xres residual + LayerNorm(b1=gamma, b2=beta),
//         fp32 out; requires BN == N == 512 (block owns full rows)
// 8 waves (512 thr) in WMxWN grid; wave tile must be 64x64; K%32==0, K/32>=3.
template <int MODE, int BM, int BN, int WM, int WN>
__global__ __launch_bounds__(512, 4) void gemm_k(
    const uint16_t* __restrict__ A, const uint16_t* __restrict__ Bt,
    void* __restrict__ OutA, uint16_t* __restrict__ OutK,
    uint16_t* __restrict__ OutVT, float* __restrict__ rsum, int K, int lda,
    int ldb, const float* __restrict__ b0, const float* __restrict__ b1,
    const float* __restrict__ b2, const float* __restrict__ Xres, float scale) {
  constexpr int MT = (BM / WM) / 16;   // acc tiles per wave, m dim
  constexpr int NT = (BN / WN) / 16;   // acc tiles per wave, n dim
  static_assert(MT == 4 && NT == 4, "wave tile must be 64x64");
  constexpr int AI = (BM >= 128) ? BM / 128 : 1;  // A gld16 issues per wave
  constexpr int BI = BN / 128;         // B gld16 issues per wave per k-tile
  constexpr int PW = AI + BI;          // this wave's loads per k-tile
  __shared__ alignas(16) uint16_t As[3][BM * 32];
  __shared__ alignas(16) uint16_t Bs[3][BN * 32];

  const int tid = threadIdx.x;
  const int w = tid >> 6, lane = tid & 63;
  const int wm = w / WN, wn = w % WN;

  // bijective XCD chunk swizzle (m204): consecutive logical tiles -> same XCD
  // L2. All grids here have nwg % 8 == 0.
  const int gx = gridDim.x, gy = gridDim.y;
  const int nwg = gx * gy * gridDim.z;
  const int hw = blockIdx.x + gx * (blockIdx.y + gy * blockIdx.z);
  const int lg = (hw & 7) * (nwg >> 3) + (hw >> 3);
  const int bx = lg % gx, byz = lg / gx;
  const int by = byz % gy, z = byz / gy;

  const int m0 = by * BM, n0 = bx * BN;

  const uint16_t* Ab = A;
  const uint16_t* Bb = Bt;
  if (MODE == 1) { Ab += (size_t)z * 2048 * 512;  Bb += (size_t)z * 2048 * 512; }
  if (MODE == 2) { Ab += (size_t)z * 2048 * 2048; Bb += (size_t)z * 512 * 2048; }

  // staging: one wave-wide gld16 covers 16 rows x 32 k (1024B linear LDS).
  // k-chunk XOR swizzle kept from R7 (neutral; reads un-permute with swz).
  // BM=64 (MODE 4): only 4 A-issue slots; waves 4-7 redundantly re-stage
  // (same global addr, same LDS dest) to keep PW uniform across waves.
  const int kc = (((lane & 3) ^ ((lane >> 2) & 3) ^ (lane >> 4)) * 8);
  const int rbA = (BM >= 128) ? w * (BM / 8) : (w & 3) * 16;
  const int rbB = w * (BN / 8);             // this wave's B row base
  const uint16_t* gA = Ab + (size_t)(m0 + rbA + (lane >> 2)) * lda + kc;
  const uint16_t* gB = Bb + (size_t)(n0 + rbB + (lane >> 2)) * ldb + kc;

  f32x4 acc[MT][NT];
#pragma unroll
  for (int i = 0; i < MT; i++)
#pragma unroll
    for (int j = 0; j < NT; j++) acc[i][j] = (f32x4){0.f, 0.f, 0.f, 0.f};

  const int lr = lane & 15, q4 = lane >> 4;
  const int swz = (((lane >> 4) ^ (lr & 3) ^ (lr >> 2)) * 8);
  const int iters = K >> 5;

  auto stage = [&](int t, int buf) {
    const int k0 = t * 32;
#pragma unroll
    for (int j = 0; j < AI; j++)
      gld16(gA + k0 + (size_t)(j * 16) * lda, &As[buf][(rbA + j * 16) * 32]);
#pragma unroll
    for (int j = 0; j < BI; j++)
      gld16(gB + k0 + (size_t)(j * 16) * ldb, &Bs[buf][(rbB + j * 16) * 32]);
  };

  auto compute = [&](int buf) {
    bf16x8 af[MT], bfr[NT];
#pragma unroll
    for (int t = 0; t < MT; t++)
      af[t] = *(const bf16x8*)&As[buf][(wm * (BM / WM) + t * 16 + lr) * 32 + swz];
#pragma unroll
    for (int t = 0; t < NT; t++)
      bfr[t] = *(const bf16x8*)&Bs[buf][(wn * (BN / WN) + t * 16 + lr) * 32 + swz];
#pragma unroll
    for (int nt = 0; nt < NT; nt++)
#pragma unroll
      for (int mt = 0; mt < MT; mt++)
        acc[mt][nt] = __builtin_amdgcn_mfma_f32_16x16x32_bf16(
            af[mt], bfr[nt], acc[mt][nt], 0, 0, 0);
  };

  // ---- depth-2 pipelined K-loop (R7/R10 shape): 1 barrier/iter, next
  // tile's loads stay in flight across it; vmcnt never 0 mid-loop ----
  stage(0, 0);
  stage(1, 1);
  int buf = 0;
  for (int i = 0; i < iters - 1; ++i) {
    asm volatile("s_waitcnt vmcnt(%0)" ::"i"(PW) : "memory");
    __builtin_amdgcn_s_barrier();   // tile i visible; buf of tile i-1 free
    if (i + 2 < iters) stage(i + 2, (buf + 2 >= 3) ? buf - 1 : buf + 2);
    compute(buf);
    buf = (buf == 2) ? 0 : buf + 1;
  }
  asm volatile("s_waitcnt vmcnt(0)" ::: "memory");
  __builtin_amdgcn_s_barrier();
  compute(buf);

  // epilogue: C/D layout col=lane&15, row=quad*4+reg  (m89/m91 verified)
  if (MODE == 1) {
    uint16_t* Sp = (uint16_t*)OutA + (size_t)z * 2048 * 2048;
#pragma unroll
    for (int mt = 0; mt < MT; mt++) {
      float rp[4] = {0.f, 0.f, 0.f, 0.f};
#pragma unroll
      for (int nt = 0; nt < NT; nt++) {
#pragma unroll
        for (int i = 0; i < 4; i++) {
          const int row = m0 + wm * (BM / WM) + mt * 16 + q4 * 4 + i;
          const int col = n0 + wn * (BN / WN) + nt * 16 + lr;
          const float e = __expf(acc[mt][nt][i] * scale);
          Sp[(size_t)row * 2048 + col] = f2bf(e);
          rp[i] += e;
        }
      }
#pragma unroll
      for (int i = 0; i < 4; i++) {
        float p = rp[i];
        p += __shfl_xor(p, 1); p += __shfl_xor(p, 2);
        p += __shfl_xor(p, 4); p += __shfl_xor(p, 8);
        if (lr == 0) {
          const int row = m0 + wm * (BM / WM) + mt * 16 + q4 * 4 + i;
          atomicAdd(&rsum[z * 2048 + row], p);
        }
      }
    }
  } else if (MODE == 2) {
#pragma unroll
    for (int mt = 0; mt < MT; mt++) {
#pragma unroll
      for (int i = 0; i < 4; i++) {
        const int row = m0 + wm * (BM / WM) + mt * 16 + q4 * 4 + i;
        const float sc = 1.0f / rsum[z * 2048 + row];
#pragma unroll
        for (int nt = 0; nt < NT; nt++) {
          const int col = n0 + wn * (BN / WN) + nt * 16 + lr;
          ((uint16_t*)OutA)[((size_t)z * 2048 + row) * 512 + col] =
              f2bf(acc[mt][nt][i] * sc);
        }
      }
    }
  } else if (MODE == 4) {
    // fused: v = acc + bo + X; LayerNorm over the full 512-row (this block
    // owns it: wm==0, 8 waves span cols); write normed fp32.
    __shared__ float redS[8][64];
    __shared__ float redQ[8][64];
    float* Op = (float*)OutA;
    __syncthreads();   // all waves done reading As/Bs fragments
#pragma unroll
    for (int mt = 0; mt < MT; mt++) {
#pragma unroll
      for (int i = 0; i < 4; i++) {
        const int rl = mt * 16 + q4 * 4 + i;
        const int row = m0 + rl;
        float ps = 0.f, pq = 0.f;
#pragma unroll
        for (int nt = 0; nt < NT; nt++) {
          const int col = wn * 64 + nt * 16 + lr;
          float v = acc[mt][nt][i] + b0[col] + Xres[(size_t)row * 512 + col];
          acc[mt][nt][i] = v;
          ps += v; pq += v * v;
        }
        ps += __shfl_xor(ps, 1); pq += __shfl_xor(pq, 1);
        ps += __shfl_xor(ps, 2); pq += __shfl_xor(pq, 2);
        ps += __shfl_xor(ps, 4); pq += __shfl_xor(pq, 4);
        ps += __shfl_xor(ps, 8); pq += __shfl_xor(pq, 8);
        if (lr == 0) { redS[w][rl] = ps; redQ[w][rl] = pq; }
      }
    }
    __syncthreads();
#pragma unroll
    for (int mt = 0; mt < MT; mt++) {
#pragma unroll
      for (int i = 0; i < 4; i++) {
        const int rl = mt * 16 + q4 * 4 + i;
        const int row = m0 + rl;
        float s8 = 0.f, q8 = 0.f;
#pragma unroll
        for (int ww = 0; ww < 8; ww++) { s8 += redS[ww][rl]; q8 += redQ[ww][rl]; }
        const float mean = s8 * (1.f / 512.f);
        const float var = q8 * (1.f / 512.f) - mean * mean;
        const float rstd = rsqrtf(var + 1e-5f);
#pragma unroll
        for (int nt = 0; nt < NT; nt++) {
          const int col = wn * 64 + nt * 16 + lr;
          Op[(size_t)row * 512 + col] =
              (acc[mt][nt][i] - mean) * rstd * b1[col] + b2[col];
        }
      }
    }
  } else {  // MODE 0
#pragma unroll
    for (int mt = 0; mt < MT; mt++) {
#pragma unroll
      for (int nt = 0; nt < NT; nt++) {
#pragma unroll
        for (int i = 0; i < 4; i++) {
          const int row = m0 + wm * (BM / WM) + mt * 16 + q4 * 4 + i;
          const int col = n0 + wn * (BN / WN) + nt * 16 + lr;
          const float v = acc[mt][nt][i];
          const int which = col >> 9, c = col & 511;
          if (which == 0) {
            ((uint16_t*)OutA)[(size_t)row * 512 + c] = f2bf(v + b0[c]);
          } else if (which == 1) {
            OutK[(size_t)row * 512 + c] = f2bf(v + b1[c]);
          } else {  // v -> transposed vT[b][h][t]
            OutVT[(size_t)(row >> 11) * (512 * 2048) + (size_t)c * 2048 +
                  (row & 2047)] = f2bf(v + b2[c]);
          }
        }
      }
    }
  }
}

// Fused conversions: X fp32->bf16 (8.39M elems, 4/thread), Wt transpose
// (first 1.05M threads), rowsum zeroing (first 16384 threads).
__global__ __launch_bounds__(256) void cvt_all_k(
    const float* __restrict__ X, uint16_t* __restrict__ Xb,
    const float* __restrict__ Wq, const float* __restrict__ Wk,
    const float* __restrict__ Wv, const float* __restrict__ Wo,
    uint16_t* __restrict__ Wt, float* __restrict__ rsum) {
  const int i = blockIdx.x * 256 + threadIdx.x;   // 0..2097151
  const float4 f = ((const float4*)X)[i];
  uint32_t lo = (uint32_t)f2bf(f.x) | ((uint32_t)f2bf(f.y) << 16);
  uint32_t hi = (uint32_t)f2bf(f.z) | ((uint32_t)f2bf(f.w) << 16);
  ((uint2*)Xb)[i] = make_uint2(lo, hi);
  if (i < 16384) rsum[i] = 0.f;
  if (i < 2048 * 512) {   // Wt[n][k] = W[k][n&511]
    const int n = i >> 9, kk = i & 511;
    const int which = n >> 9, c = n & 511;
    const float* W =
        (which == 0) ? Wq : (which == 1) ? Wk : (which == 2) ? Wv : Wo;
    Wt[i] = f2bf(W[kk * 512 + c]);
  }
}

extern "C" void kernel_launch(void* const* d_in, const int* in_sizes, int n_in,
                              void* d_out, int out_size, void* d_ws,
                              size_t ws_size, hipStream_t stream) {
  const float* X     = (const float*)d_in[0];
  const float* Wq    = (const float*)d_in[1];
  const float* bq    = (const float*)d_in[2];
  const float* Wk    = (const float*)d_in[3];
  const float* bk    = (const float*)d_in[4];
  const float* Wv    = (const float*)d_in[5];
  const float* bv    = (const float*)d_in[6];
  const float* Wo    = (const float*)d_in[7];
  const float* bo    = (const float*)d_in[8];
  const float* gamma = (const float*)d_in[9];
  const float* beta  = (const float*)d_in[10];
  float* out = (float*)d_out;

  char* ws = (char*)d_ws;   // ~114.1 MB used (overlaid layout, see header)
  uint16_t* S    = (uint16_t*)(ws);                 // [0, 64M)
  uint16_t* Xb   = (uint16_t*)(ws);                 // [0, 16M) overlay on S
  uint16_t* Wt   = (uint16_t*)(ws + 67108864);      // [64M, 66M)
  uint16_t* q    = (uint16_t*)(ws + 69206016);      // [66M, 82M), later ctx
  uint16_t* kb   = (uint16_t*)(ws + 85983232);      // [82M, 98M)
  uint16_t* vT   = (uint16_t*)(ws + 102760448);     // [98M, 114M) [8][512][2048]
  float*    rsum = (float*)(ws + 119537664);        // [114M, +64K) fp32[16384]
  uint16_t* ctx  = q;                               // overlay: q dead after scores

  cvt_all_k<<<dim3(8192), dim3(256), 0, stream>>>(X, Xb, Wq, Wk, Wv, Wo, Wt,
                                                  rsum);
  // QKV: M=16384, N=1536, K=512, tile 256x128 (768 blocks)
  gemm_k<0, 256, 128, 4, 2><<<dim3(12, 64, 1), dim3(512), 0, stream>>>(
      Xb, Wt, (void*)q, kb, vT, nullptr, 512, 512, 512, bq, bk, bv, nullptr,
      1.f);
  // scores: per batch M=N=2048, K=512; tile 256x128 (1024 blocks)
  gemm_k<1, 256, 128, 4, 2><<<dim3(16, 8, 8), dim3(512), 0, stream>>>(
      q, kb, (void*)S, nullptr, nullptr, rsum, 512, 512, 512, nullptr, nullptr,
      nullptr, nullptr, 0.044194173824159216f);
  // ctx = (E @ V)/rowsum: per batch M=2048, N=512, K=2048, tile 256x128
  gemm_k<2, 256, 128, 4, 2><<<dim3(4, 8, 8), dim3(512), 0, stream>>>(
      S, vT, (void*)ctx, nullptr, nullptr, rsum, 2048, 2048, 2048, nullptr,
      nullptr, nullptr, nullptr, 1.f);
  // fused out-proj + bo + X residual + LayerNorm: M=16384, N=512, K=512,
  // tile 64x512 (256 blocks, each owns full rows)
  gemm_k<4, 64, 512, 1, 8><<<dim3(1, 256, 1), dim3(512), 0, stream>>>(
      ctx, Wt + 1536 * 512, (void*)out, nullptr, nullptr, nullptr, 512, 512,
      512, bo, gamma, beta, X, 1.f);
}